// Round 4
// baseline (985.727 us; speedup 1.0000x reference)
//
#include <hip/hip_runtime.h>
#include <hip/hip_bf16.h>
#include <cstdint>
#include <cstddef>

typedef __hip_bfloat16 BF;
typedef __attribute__((ext_vector_type(8))) short bhalf8;   // 8 bf16 (MFMA A/B frag)
typedef __attribute__((ext_vector_type(4))) float floatx4;  // MFMA C/D frag

#define NB 8
#define NC 512
#define NHW 4096
#define NG 32

__device__ __forceinline__ float b2f(short h) {
    union { unsigned u; float f; } c;
    c.u = ((unsigned)(unsigned short)h) << 16;
    return c.f;
}
__device__ __forceinline__ short f2b(float f) {
    __hip_bfloat16 h = __float2bfloat16(f);
    short s;
    __builtin_memcpy(&s, &h, 2);
    return s;
}

// 16B global -> LDS direct (wave-uniform LDS base + lane*16)
__device__ __forceinline__ void gload16(const BF* g, BF* l) {
    __builtin_amdgcn_global_load_lds(
        (const __attribute__((address_space(1))) void*)g,
        (__attribute__((address_space(3))) void*)l, 16, 0, 0);
}

// ---------------------------------------------------------------------------
__global__ __launch_bounds__(256) void f2b_convert(const float* __restrict__ src,
                                                   BF* __restrict__ dst, int n) {
    int i = (blockIdx.x * 256 + threadIdx.x) * 4;
    if (i >= n) return;
    float4 v = *(const float4*)&src[i];
    dst[i]     = __float2bfloat16(v.x);
    dst[i + 1] = __float2bfloat16(v.y);
    dst[i + 2] = __float2bfloat16(v.z);
    dst[i + 3] = __float2bfloat16(v.w);
}

// ---------------------------------------------------------------------------
__global__ __launch_bounds__(256) void gn_stats(const float* __restrict__ x,
                                                float* __restrict__ stats) {
    const int bg = blockIdx.x;
    const long base = (long)bg * 65536;
    float s = 0.f, q = 0.f;
    for (int i = threadIdx.x * 4; i < 65536; i += 256 * 4) {
        float4 v4 = *(const float4*)&x[base + i];
        s += v4.x + v4.y + v4.z + v4.w;
        q += v4.x * v4.x + v4.y * v4.y + v4.z * v4.z + v4.w * v4.w;
    }
#pragma unroll
    for (int o = 32; o; o >>= 1) { s += __shfl_down(s, o); q += __shfl_down(q, o); }
    __shared__ float rs[4], rq[4];
    const int w = threadIdx.x >> 6;
    if ((threadIdx.x & 63) == 0) { rs[w] = s; rq[w] = q; }
    __syncthreads();
    if (threadIdx.x == 0) {
        s = rs[0] + rs[1] + rs[2] + rs[3];
        q = rq[0] + rq[1] + rq[2] + rq[3];
        float mean = s * (1.f / 65536.f);
        float var = q * (1.f / 65536.f) - mean * mean;
        stats[2 * bg]     = mean;
        stats[2 * bg + 1] = rsqrtf(fmaxf(var, 0.f) + 1e-6f);
    }
}

// ---------------------------------------------------------------------------
__global__ __launch_bounds__(256) void gn_apply(const float* __restrict__ x,
                                                const float* __restrict__ gamma,
                                                const float* __restrict__ beta,
                                                const float* __restrict__ stats,
                                                BF* __restrict__ n) {
    __shared__ float tile[64][65];
    const int b = blockIdx.z, c0 = blockIdx.y * 64, s0 = blockIdx.x * 64;
    const long xbase = ((long)b * NC + c0) * NHW + s0;
#pragma unroll
    for (int i = 0; i < 16; i++) {
        int lin = i * 256 + threadIdx.x;
        int cl = lin >> 6, sl = lin & 63;
        int c = c0 + cl;
        float2 mr = ((const float2*)stats)[b * NG + (c >> 4)];
        float v = x[xbase + (long)cl * NHW + sl];
        v = (v - mr.x) * mr.y * gamma[c] + beta[c];
        tile[cl][sl] = v;
    }
    __syncthreads();
    const long nbase = ((long)b * NHW + s0) * NC + c0;
#pragma unroll
    for (int i = 0; i < 16; i++) {
        int lin = i * 256 + threadIdx.x;
        int sl = lin >> 6, cl = lin & 63;
        n[nbase + (long)sl * NC + cl] = __float2bfloat16(tile[cl][sl]);
    }
}

// ---------------------------------------------------------------------------
// S-GEMM: S[m][n] = scale * sum_k Q[m][k] K[n][k]. 128x128 tile, BK=32,
// m97 staging, 3 blocks/CU.
// ---------------------------------------------------------------------------
__global__ __launch_bounds__(256, 3) void sgemm(
    const BF* __restrict__ A, long aStride,
    const BF* __restrict__ Bm, long bStride,
    BF* __restrict__ C, long cStride,
    int M, int N, int K, float scale)
{
    __shared__ __align__(16) BF sA[128 * 32];
    __shared__ __align__(16) BF sB[128 * 32];
    const int tid = threadIdx.x;
    const int wave = tid >> 6, lane = tid & 63;
    const int bm = blockIdx.y * 128, bn = blockIdx.x * 128;
    const BF* Ab = A + (long)blockIdx.z * aStride + (long)bm * K;
    const BF* Bb = Bm + (long)blockIdx.z * bStride + (long)bn * K;

    const int srow = wave * 32 + (lane >> 2);
    const int sk = (lane & 3) * 8;
    const BF* gA0 = Ab + (long)srow * K + sk;
    const BF* gA1 = gA0 + (long)16 * K;
    const BF* gB0 = Bb + (long)srow * K + sk;
    const BF* gB1 = gB0 + (long)16 * K;
    BF* lA0 = &sA[(wave * 32) * 32];
    BF* lA1 = &sA[(wave * 32 + 16) * 32];
    BF* lB0 = &sB[(wave * 32) * 32];
    BF* lB1 = &sB[(wave * 32 + 16) * 32];

    floatx4 acc[4][4];
#pragma unroll
    for (int i = 0; i < 4; i++)
#pragma unroll
        for (int j = 0; j < 4; j++) acc[i][j] = (floatx4){0.f, 0.f, 0.f, 0.f};

    const int wm = (wave >> 1) * 64, wn = (wave & 1) * 64;
    const int lr = lane & 15, lk = (lane >> 4) * 8;

    for (int k0 = 0; k0 < K; k0 += 32) {
        __syncthreads();
        gload16(gA0 + k0, lA0);
        gload16(gA1 + k0, lA1);
        gload16(gB0 + k0, lB0);
        gload16(gB1 + k0, lB1);
        __syncthreads();
        bhalf8 af[4], bfr[4];
#pragma unroll
        for (int i = 0; i < 4; i++)
            af[i] = *(const bhalf8*)&sA[(wm + i * 16 + lr) * 32 + lk];
#pragma unroll
        for (int i = 0; i < 4; i++)
            bfr[i] = *(const bhalf8*)&sB[(wn + i * 16 + lr) * 32 + lk];
#pragma unroll
        for (int mi = 0; mi < 4; mi++)
#pragma unroll
            for (int ni = 0; ni < 4; ni++)
                acc[mi][ni] = __builtin_amdgcn_mfma_f32_16x16x32_bf16(
                    af[mi], bfr[ni], acc[mi][ni], 0, 0, 0);
    }

    BF* Cb = C + (long)blockIdx.z * cStride;
#pragma unroll
    for (int ni = 0; ni < 4; ni++) {
        const int col = bn + wn + ni * 16 + lr;
#pragma unroll
        for (int mi = 0; mi < 4; mi++) {
            const int row0 = bm + wm + mi * 16 + (lane >> 4) * 4;
#pragma unroll
            for (int r = 0; r < 4; r++)
                Cb[(long)(row0 + r) * N + col] = __float2bfloat16(acc[mi][ni][r] * scale);
        }
    }
}

// ---------------------------------------------------------------------------
// Fused QKV GEMM: A = n [4096,512], B = wqkv [1536,512] (rows: Wq|Wk|Wv).
// Section (by bn>>9): 0 -> q[i][c], 1 -> kk[i][c], 2 -> vT[c][i]; + bias.
// Grid (12, 32, 8).
// ---------------------------------------------------------------------------
__global__ __launch_bounds__(256, 3) void qkv_gemm(
    const BF* __restrict__ A, const BF* __restrict__ Bm,
    BF* __restrict__ q, BF* __restrict__ kk, BF* __restrict__ vT,
    const float* __restrict__ bq, const float* __restrict__ bk,
    const float* __restrict__ bv)
{
    const int K = NC;
    __shared__ __align__(16) BF sA[128 * 32];
    __shared__ __align__(16) BF sB[128 * 32];
    const int tid = threadIdx.x;
    const int wave = tid >> 6, lane = tid & 63;
    const int bm = blockIdx.y * 128, bn = blockIdx.x * 128;
    const long ACTB = (long)NHW * NC;
    const BF* Ab = A + blockIdx.z * ACTB + (long)bm * K;
    const BF* Bb = Bm + (long)bn * K;

    const int srow = wave * 32 + (lane >> 2);
    const int sk = (lane & 3) * 8;
    const BF* gA0 = Ab + (long)srow * K + sk;
    const BF* gA1 = gA0 + (long)16 * K;
    const BF* gB0 = Bb + (long)srow * K + sk;
    const BF* gB1 = gB0 + (long)16 * K;
    BF* lA0 = &sA[(wave * 32) * 32];
    BF* lA1 = &sA[(wave * 32 + 16) * 32];
    BF* lB0 = &sB[(wave * 32) * 32];
    BF* lB1 = &sB[(wave * 32 + 16) * 32];

    floatx4 acc[4][4];
#pragma unroll
    for (int i = 0; i < 4; i++)
#pragma unroll
        for (int j = 0; j < 4; j++) acc[i][j] = (floatx4){0.f, 0.f, 0.f, 0.f};

    const int wm = (wave >> 1) * 64, wn = (wave & 1) * 64;
    const int lr = lane & 15, lk = (lane >> 4) * 8;

    for (int k0 = 0; k0 < K; k0 += 32) {
        __syncthreads();
        gload16(gA0 + k0, lA0);
        gload16(gA1 + k0, lA1);
        gload16(gB0 + k0, lB0);
        gload16(gB1 + k0, lB1);
        __syncthreads();
        bhalf8 af[4], bfr[4];
#pragma unroll
        for (int i = 0; i < 4; i++)
            af[i] = *(const bhalf8*)&sA[(wm + i * 16 + lr) * 32 + lk];
#pragma unroll
        for (int i = 0; i < 4; i++)
            bfr[i] = *(const bhalf8*)&sB[(wn + i * 16 + lr) * 32 + lk];
#pragma unroll
        for (int mi = 0; mi < 4; mi++)
#pragma unroll
            for (int ni = 0; ni < 4; ni++)
                acc[mi][ni] = __builtin_amdgcn_mfma_f32_16x16x32_bf16(
                    af[mi], bfr[ni], acc[mi][ni], 0, 0, 0);
    }

    const int sec = bn >> 9;                    // 0=Q 1=K 2=V (uniform per block)
    const float* bp = (sec == 0) ? bq : (sec == 1) ? bk : bv;
    BF* dst = (sec == 0) ? q : (sec == 1) ? kk : vT;
    dst += blockIdx.z * ACTB;
    const int cb = bn & 511;
#pragma unroll
    for (int ni = 0; ni < 4; ni++) {
        const int col = cb + wn + ni * 16 + lr;
        const float bias = bp[col];
#pragma unroll
        for (int mi = 0; mi < 4; mi++) {
            const int row0 = bm + wm + mi * 16 + (lane >> 4) * 4;
#pragma unroll
            for (int r = 0; r < 4; r++) {
                float v = acc[mi][ni][r] + bias;
                if (sec == 2) dst[(long)col * NHW + row0 + r] = __float2bfloat16(v);
                else          dst[(long)(row0 + r) * NC + col] = __float2bfloat16(v);
            }
        }
    }
}

// ---------------------------------------------------------------------------
// Wo GEMM + transpose + residual: out[b][f][i] = sum_c attn[i][c] Wo[f][c] + x.
// fp32 float4 stores. Grid (4, 32, 8).
// ---------------------------------------------------------------------------
__global__ __launch_bounds__(256, 3) void wo_gemm(
    const BF* __restrict__ A, const BF* __restrict__ Bm,
    const float* __restrict__ x, float* __restrict__ out)
{
    const int K = NC;
    __shared__ __align__(16) BF sA[128 * 32];
    __shared__ __align__(16) BF sB[128 * 32];
    const int tid = threadIdx.x;
    const int wave = tid >> 6, lane = tid & 63;
    const int bm = blockIdx.y * 128, bn = blockIdx.x * 128;
    const long ACTB = (long)NHW * NC;
    const BF* Ab = A + blockIdx.z * ACTB + (long)bm * K;
    const BF* Bb = Bm + (long)bn * K;

    const int srow = wave * 32 + (lane >> 2);
    const int sk = (lane & 3) * 8;
    const BF* gA0 = Ab + (long)srow * K + sk;
    const BF* gA1 = gA0 + (long)16 * K;
    const BF* gB0 = Bb + (long)srow * K + sk;
    const BF* gB1 = gB0 + (long)16 * K;
    BF* lA0 = &sA[(wave * 32) * 32];
    BF* lA1 = &sA[(wave * 32 + 16) * 32];
    BF* lB0 = &sB[(wave * 32) * 32];
    BF* lB1 = &sB[(wave * 32 + 16) * 32];

    floatx4 acc[4][4];
#pragma unroll
    for (int i = 0; i < 4; i++)
#pragma unroll
        for (int j = 0; j < 4; j++) acc[i][j] = (floatx4){0.f, 0.f, 0.f, 0.f};

    const int wm = (wave >> 1) * 64, wn = (wave & 1) * 64;
    const int lr = lane & 15, lk = (lane >> 4) * 8;

    for (int k0 = 0; k0 < K; k0 += 32) {
        __syncthreads();
        gload16(gA0 + k0, lA0);
        gload16(gA1 + k0, lA1);
        gload16(gB0 + k0, lB0);
        gload16(gB1 + k0, lB1);
        __syncthreads();
        bhalf8 af[4], bfr[4];
#pragma unroll
        for (int i = 0; i < 4; i++)
            af[i] = *(const bhalf8*)&sA[(wm + i * 16 + lr) * 32 + lk];
#pragma unroll
        for (int i = 0; i < 4; i++)
            bfr[i] = *(const bhalf8*)&sB[(wn + i * 16 + lr) * 32 + lk];
#pragma unroll
        for (int mi = 0; mi < 4; mi++)
#pragma unroll
            for (int ni = 0; ni < 4; ni++)
                acc[mi][ni] = __builtin_amdgcn_mfma_f32_16x16x32_bf16(
                    af[mi], bfr[ni], acc[mi][ni], 0, 0, 0);
    }

    const float* xb = x + blockIdx.z * ACTB;
    float* ob = out + blockIdx.z * ACTB;
#pragma unroll
    for (int ni = 0; ni < 4; ni++) {
        const int col = bn + wn + ni * 16 + lr;      // channel f
#pragma unroll
        for (int mi = 0; mi < 4; mi++) {
            const int row0 = bm + wm + mi * 16 + (lane >> 4) * 4;   // spatial i
            const long a = (long)col * NHW + row0;
            float4 xr = *(const float4*)&xb[a];
            float4 o;
            o.x = acc[mi][ni][0] + xr.x;
            o.y = acc[mi][ni][1] + xr.y;
            o.z = acc[mi][ni][2] + xr.z;
            o.w = acc[mi][ni][3] + xr.w;
            *(float4*)&ob[a] = o;
        }
    }
}

// ---------------------------------------------------------------------------
// PV GEMM: attn[i][c] = sum_j P[i][j] vT[c][j].  Block tile M=32 x N=512
// (full C width -> P read exactly once). Grid (NHW/32, chunk).
// 4 waves: wave w covers cols [w*128, w*128+128), all 32 rows.
// ---------------------------------------------------------------------------
__global__ __launch_bounds__(256, 2) void pv512(
    const BF* __restrict__ S, const BF* __restrict__ vT,
    BF* __restrict__ attn)
{
    __shared__ __align__(16) BF sA[32 * 32];     // P tile: 32 i x 32 j
    __shared__ __align__(16) BF sB[512 * 32];    // V tile: 512 c x 32 j
    const int tid = threadIdx.x;
    const int wave = tid >> 6, lane = tid & 63;
    const int bm = blockIdx.x * 32;
    const long SB = (long)NHW * NHW, ACTB = (long)NHW * NC;
    const BF* Sb = S + blockIdx.y * SB + (long)bm * NHW;
    const BF* Vb = vT + blockIdx.y * ACTB;
    BF* Ab = attn + blockIdx.y * ACTB + (long)bm * NC;

    const int rowoff = lane >> 2, sk = (lane & 3) * 8;
    // A staging: waves 0,1 cover rows 0-15 / 16-31
    const BF* gA = Sb + (long)(wave * 16 + rowoff) * NHW + sk;
    BF* lA = &sA[(wave * 16) * 32];
    // B staging: wave w covers c in [w*128, w*128+128), 8 instrs of 16 rows
    const BF* gB = Vb + (long)(wave * 128 + rowoff) * NHW + sk;
    BF* lB = &sB[(wave * 128) * 32];

    floatx4 acc[2][8];
#pragma unroll
    for (int i = 0; i < 2; i++)
#pragma unroll
        for (int j = 0; j < 8; j++) acc[i][j] = (floatx4){0.f, 0.f, 0.f, 0.f};

    const int lr = lane & 15, lk = (lane >> 4) * 8;

    for (int j0 = 0; j0 < NHW; j0 += 32) {
        __syncthreads();
        if (wave < 2) gload16(gA + j0, lA);
#pragma unroll
        for (int it = 0; it < 8; it++)
            gload16(gB + (long)it * 16 * NHW + j0, lB + it * 16 * 32);
        __syncthreads();
        bhalf8 af[2], bfr[8];
#pragma unroll
        for (int i = 0; i < 2; i++)
            af[i] = *(const bhalf8*)&sA[(i * 16 + lr) * 32 + lk];
#pragma unroll
        for (int i = 0; i < 8; i++)
            bfr[i] = *(const bhalf8*)&sB[(wave * 128 + i * 16 + lr) * 32 + lk];
#pragma unroll
        for (int mi = 0; mi < 2; mi++)
#pragma unroll
            for (int ni = 0; ni < 8; ni++)
                acc[mi][ni] = __builtin_amdgcn_mfma_f32_16x16x32_bf16(
                    af[mi], bfr[ni], acc[mi][ni], 0, 0, 0);
    }

#pragma unroll
    for (int ni = 0; ni < 8; ni++) {
        const int col = wave * 128 + ni * 16 + lr;
#pragma unroll
        for (int mi = 0; mi < 2; mi++) {
            const int row0 = mi * 16 + (lane >> 4) * 4;
#pragma unroll
            for (int r = 0; r < 4; r++)
                Ab[(long)(row0 + r) * NC + col] = __float2bfloat16(acc[mi][ni][r]);
        }
    }
}

// ---------------------------------------------------------------------------
__global__ __launch_bounds__(256) void softmax4096(BF* __restrict__ S) {
    const long base = (long)blockIdx.x * 4096 + threadIdx.x * 16;
    const int tid = threadIdx.x, w = tid >> 6;
    bhalf8 u = *(bhalf8*)&S[base];
    bhalf8 u2 = *(bhalf8*)&S[base + 8];
    float v[16];
    float m = -1e30f;
#pragma unroll
    for (int j = 0; j < 8; j++) { v[j] = b2f(u[j]); v[8 + j] = b2f(u2[j]); }
#pragma unroll
    for (int j = 0; j < 16; j++) m = fmaxf(m, v[j]);
#pragma unroll
    for (int o = 32; o; o >>= 1) m = fmaxf(m, __shfl_xor(m, o));
    __shared__ float rm[4], rs[4];
    if ((tid & 63) == 0) rm[w] = m;
    __syncthreads();
    m = fmaxf(fmaxf(rm[0], rm[1]), fmaxf(rm[2], rm[3]));
    float s = 0.f;
#pragma unroll
    for (int j = 0; j < 16; j++) { v[j] = __expf(v[j] - m); s += v[j]; }
#pragma unroll
    for (int o = 32; o; o >>= 1) s += __shfl_xor(s, o);
    if ((tid & 63) == 0) rs[w] = s;
    __syncthreads();
    s = rs[0] + rs[1] + rs[2] + rs[3];
    const float inv = 1.0f / s;
#pragma unroll
    for (int j = 0; j < 8; j++) { u[j] = f2b(v[j] * inv); u2[j] = f2b(v[8 + j] * inv); }
    *(bhalf8*)&S[base] = u;
    *(bhalf8*)&S[base + 8] = u2;
}

// ---------------------------------------------------------------------------
extern "C" void kernel_launch(void* const* d_in, const int* in_sizes, int n_in,
                              void* d_out, int out_size, void* d_ws, size_t ws_size,
                              hipStream_t stream) {
    const float* x     = (const float*)d_in[0];
    const float* gamma = (const float*)d_in[1];
    const float* beta  = (const float*)d_in[2];
    const float* Wq    = (const float*)d_in[3];
    const float* bq    = (const float*)d_in[4];
    const float* Wk    = (const float*)d_in[5];
    const float* bk    = (const float*)d_in[6];
    const float* Wv    = (const float*)d_in[7];
    const float* bv    = (const float*)d_in[8];
    const float* Wo    = (const float*)d_in[9];
    float* out = (float*)d_out;

    const long ACTB = (long)NHW * NC;        // 2M elems / batch
    const long SB   = (long)NHW * NHW;       // 16.7M elems / batch
    const long WSZ  = (long)NC * NC;

    char* ws = (char*)d_ws;
    float* stats = (float*)ws;
    BF* wb = (BF*)(ws + 4096);               // [Wq|Wk|Wv] as [1536,512], then Wo
    BF* q  = wb + 4 * WSZ;
    BF* kk = q + NB * ACTB;
    BF* vT = kk + NB * ACTB;
    BF* R  = vT + NB * ACTB;                 // n, then S (disjoint lifetimes)
    BF* n = R;
    BF* S = R;

    const size_t base_need = 4096ull + (size_t)4 * WSZ * 2 + (size_t)3 * NB * ACTB * 2;
    long sroom = (ws_size > base_need) ? (long)((ws_size - base_need) / (SB * 2)) : 1;
    int chunk = (int)(sroom < 1 ? 1 : (sroom > NB ? NB : sroom));
    while (NB % chunk) chunk--;              // 8,4,2,1

    f2b_convert<<<256, 256, 0, stream>>>(Wq, wb + 0 * WSZ, (int)WSZ);
    f2b_convert<<<256, 256, 0, stream>>>(Wk, wb + 1 * WSZ, (int)WSZ);
    f2b_convert<<<256, 256, 0, stream>>>(Wv, wb + 2 * WSZ, (int)WSZ);
    f2b_convert<<<256, 256, 0, stream>>>(Wo, wb + 3 * WSZ, (int)WSZ);

    gn_stats<<<NB * NG, 256, 0, stream>>>(x, stats);
    gn_apply<<<dim3(NHW / 64, NC / 64, NB), 256, 0, stream>>>(x, gamma, beta, stats, n);

    qkv_gemm<<<dim3(12, NHW / 128, NB), 256, 0, stream>>>(
        n, wb, q, kk, vT, bq, bk, bv);

    const float iscl = 0.044194173824159216f;  // 1/sqrt(512)
    for (int b0 = 0; b0 < NB; b0 += chunk) {
        sgemm<<<dim3(NHW / 128, NHW / 128, chunk), 256, 0, stream>>>(
            q + b0 * ACTB, ACTB, kk + b0 * ACTB, ACTB, S, SB,
            NHW, NHW, NC, iscl);
        softmax4096<<<NHW * chunk, 256, 0, stream>>>(S);
        pv512<<<dim3(NHW / 32, chunk), 256, 0, stream>>>(
            S, vT + b0 * ACTB, q + b0 * ACTB);     // attn overwrites Q
    }

    wo_gemm<<<dim3(NC / 128, NHW / 128, NB), 256, 0, stream>>>(
        q, wb + 3 * WSZ, x, out);
}

// Round 5
// 935.429 us; speedup vs baseline: 1.0538x; 1.0538x over previous
//
#include <hip/hip_runtime.h>
#include <hip/hip_bf16.h>
#include <cstdint>
#include <cstddef>

typedef __hip_bfloat16 BF;
typedef __attribute__((ext_vector_type(8))) short bhalf8;   // 8 bf16 (MFMA A/B frag)
typedef __attribute__((ext_vector_type(4))) float floatx4;  // MFMA C/D frag

#define NB 8
#define NC 512
#define NHW 4096
#define NG 32

__device__ __forceinline__ float b2f(short h) {
    union { unsigned u; float f; } c;
    c.u = ((unsigned)(unsigned short)h) << 16;
    return c.f;
}
__device__ __forceinline__ short f2b(float f) {
    __hip_bfloat16 h = __float2bfloat16(f);
    short s;
    __builtin_memcpy(&s, &h, 2);
    return s;
}

// 16B global -> LDS direct (wave-uniform LDS base + lane*16)
__device__ __forceinline__ void gload16(const BF* g, BF* l) {
    __builtin_amdgcn_global_load_lds(
        (const __attribute__((address_space(1))) void*)g,
        (__attribute__((address_space(3))) void*)l, 16, 0, 0);
}

// ---------------------------------------------------------------------------
__global__ __launch_bounds__(256) void f2b_convert(const float* __restrict__ src,
                                                   BF* __restrict__ dst, int n) {
    int i = (blockIdx.x * 256 + threadIdx.x) * 4;
    if (i >= n) return;
    float4 v = *(const float4*)&src[i];
    dst[i]     = __float2bfloat16(v.x);
    dst[i + 1] = __float2bfloat16(v.y);
    dst[i + 2] = __float2bfloat16(v.z);
    dst[i + 3] = __float2bfloat16(v.w);
}

// ---------------------------------------------------------------------------
__global__ __launch_bounds__(256) void gn_stats(const float* __restrict__ x,
                                                float* __restrict__ stats) {
    const int bg = blockIdx.x;
    const long base = (long)bg * 65536;
    float s = 0.f, q = 0.f;
    for (int i = threadIdx.x * 4; i < 65536; i += 256 * 4) {
        float4 v4 = *(const float4*)&x[base + i];
        s += v4.x + v4.y + v4.z + v4.w;
        q += v4.x * v4.x + v4.y * v4.y + v4.z * v4.z + v4.w * v4.w;
    }
#pragma unroll
    for (int o = 32; o; o >>= 1) { s += __shfl_down(s, o); q += __shfl_down(q, o); }
    __shared__ float rs[4], rq[4];
    const int w = threadIdx.x >> 6;
    if ((threadIdx.x & 63) == 0) { rs[w] = s; rq[w] = q; }
    __syncthreads();
    if (threadIdx.x == 0) {
        s = rs[0] + rs[1] + rs[2] + rs[3];
        q = rq[0] + rq[1] + rq[2] + rq[3];
        float mean = s * (1.f / 65536.f);
        float var = q * (1.f / 65536.f) - mean * mean;
        stats[2 * bg]     = mean;
        stats[2 * bg + 1] = rsqrtf(fmaxf(var, 0.f) + 1e-6f);
    }
}

// ---------------------------------------------------------------------------
__global__ __launch_bounds__(256) void gn_apply(const float* __restrict__ x,
                                                const float* __restrict__ gamma,
                                                const float* __restrict__ beta,
                                                const float* __restrict__ stats,
                                                BF* __restrict__ n) {
    __shared__ float tile[64][65];
    const int b = blockIdx.z, c0 = blockIdx.y * 64, s0 = blockIdx.x * 64;
    const long xbase = ((long)b * NC + c0) * NHW + s0;
#pragma unroll
    for (int i = 0; i < 16; i++) {
        int lin = i * 256 + threadIdx.x;
        int cl = lin >> 6, sl = lin & 63;
        int c = c0 + cl;
        float2 mr = ((const float2*)stats)[b * NG + (c >> 4)];
        float v = x[xbase + (long)cl * NHW + sl];
        v = (v - mr.x) * mr.y * gamma[c] + beta[c];
        tile[cl][sl] = v;
    }
    __syncthreads();
    const long nbase = ((long)b * NHW + s0) * NC + c0;
#pragma unroll
    for (int i = 0; i < 16; i++) {
        int lin = i * 256 + threadIdx.x;
        int sl = lin >> 6, cl = lin & 63;
        n[nbase + (long)sl * NC + cl] = __float2bfloat16(tile[cl][sl]);
    }
}

// ---------------------------------------------------------------------------
// S-GEMM: S[m][n] = scale * sum_k Q[m][k] K[n][k]. 128x128 tile, BK=32,
// m97 staging, 4 blocks/CU (56 VGPR + 64 AGPR = 120 <= 128/wave).
// ---------------------------------------------------------------------------
__global__ __launch_bounds__(256, 4) void sgemm(
    const BF* __restrict__ A, long aStride,
    const BF* __restrict__ Bm, long bStride,
    BF* __restrict__ C, long cStride,
    int M, int N, int K, float scale)
{
    __shared__ __align__(16) BF sA[128 * 32];
    __shared__ __align__(16) BF sB[128 * 32];
    const int tid = threadIdx.x;
    const int wave = tid >> 6, lane = tid & 63;
    const int bm = blockIdx.y * 128, bn = blockIdx.x * 128;
    const BF* Ab = A + (long)blockIdx.z * aStride + (long)bm * K;
    const BF* Bb = Bm + (long)blockIdx.z * bStride + (long)bn * K;

    const int srow = wave * 32 + (lane >> 2);
    const int sk = (lane & 3) * 8;
    const BF* gA0 = Ab + (long)srow * K + sk;
    const BF* gA1 = gA0 + (long)16 * K;
    const BF* gB0 = Bb + (long)srow * K + sk;
    const BF* gB1 = gB0 + (long)16 * K;
    BF* lA0 = &sA[(wave * 32) * 32];
    BF* lA1 = &sA[(wave * 32 + 16) * 32];
    BF* lB0 = &sB[(wave * 32) * 32];
    BF* lB1 = &sB[(wave * 32 + 16) * 32];

    floatx4 acc[4][4];
#pragma unroll
    for (int i = 0; i < 4; i++)
#pragma unroll
        for (int j = 0; j < 4; j++) acc[i][j] = (floatx4){0.f, 0.f, 0.f, 0.f};

    const int wm = (wave >> 1) * 64, wn = (wave & 1) * 64;
    const int lr = lane & 15, lk = (lane >> 4) * 8;

    for (int k0 = 0; k0 < K; k0 += 32) {
        __syncthreads();
        gload16(gA0 + k0, lA0);
        gload16(gA1 + k0, lA1);
        gload16(gB0 + k0, lB0);
        gload16(gB1 + k0, lB1);
        __syncthreads();
        bhalf8 af[4], bfr[4];
#pragma unroll
        for (int i = 0; i < 4; i++)
            af[i] = *(const bhalf8*)&sA[(wm + i * 16 + lr) * 32 + lk];
#pragma unroll
        for (int i = 0; i < 4; i++)
            bfr[i] = *(const bhalf8*)&sB[(wn + i * 16 + lr) * 32 + lk];
#pragma unroll
        for (int mi = 0; mi < 4; mi++)
#pragma unroll
            for (int ni = 0; ni < 4; ni++)
                acc[mi][ni] = __builtin_amdgcn_mfma_f32_16x16x32_bf16(
                    af[mi], bfr[ni], acc[mi][ni], 0, 0, 0);
    }

    BF* Cb = C + (long)blockIdx.z * cStride;
#pragma unroll
    for (int ni = 0; ni < 4; ni++) {
        const int col = bn + wn + ni * 16 + lr;
#pragma unroll
        for (int mi = 0; mi < 4; mi++) {
            const int row0 = bm + wm + mi * 16 + (lane >> 4) * 4;
#pragma unroll
            for (int r = 0; r < 4; r++)
                Cb[(long)(row0 + r) * N + col] = __float2bfloat16(acc[mi][ni][r] * scale);
        }
    }
}

// ---------------------------------------------------------------------------
// Fused QKV GEMM: A = n [4096,512], B = wqkv [1536,512] (rows: Wq|Wk|Wv).
// Section (by bn>>9): 0 -> q[i][c], 1 -> kk[i][c], 2 -> vT[c][i]; + bias.
// ---------------------------------------------------------------------------
__global__ __launch_bounds__(256, 4) void qkv_gemm(
    const BF* __restrict__ A, const BF* __restrict__ Bm,
    BF* __restrict__ q, BF* __restrict__ kk, BF* __restrict__ vT,
    const float* __restrict__ bq, const float* __restrict__ bk,
    const float* __restrict__ bv)
{
    const int K = NC;
    __shared__ __align__(16) BF sA[128 * 32];
    __shared__ __align__(16) BF sB[128 * 32];
    const int tid = threadIdx.x;
    const int wave = tid >> 6, lane = tid & 63;
    const int bm = blockIdx.y * 128, bn = blockIdx.x * 128;
    const long ACTB = (long)NHW * NC;
    const BF* Ab = A + blockIdx.z * ACTB + (long)bm * K;
    const BF* Bb = Bm + (long)bn * K;

    const int srow = wave * 32 + (lane >> 2);
    const int sk = (lane & 3) * 8;
    const BF* gA0 = Ab + (long)srow * K + sk;
    const BF* gA1 = gA0 + (long)16 * K;
    const BF* gB0 = Bb + (long)srow * K + sk;
    const BF* gB1 = gB0 + (long)16 * K;
    BF* lA0 = &sA[(wave * 32) * 32];
    BF* lA1 = &sA[(wave * 32 + 16) * 32];
    BF* lB0 = &sB[(wave * 32) * 32];
    BF* lB1 = &sB[(wave * 32 + 16) * 32];

    floatx4 acc[4][4];
#pragma unroll
    for (int i = 0; i < 4; i++)
#pragma unroll
        for (int j = 0; j < 4; j++) acc[i][j] = (floatx4){0.f, 0.f, 0.f, 0.f};

    const int wm = (wave >> 1) * 64, wn = (wave & 1) * 64;
    const int lr = lane & 15, lk = (lane >> 4) * 8;

    for (int k0 = 0; k0 < K; k0 += 32) {
        __syncthreads();
        gload16(gA0 + k0, lA0);
        gload16(gA1 + k0, lA1);
        gload16(gB0 + k0, lB0);
        gload16(gB1 + k0, lB1);
        __syncthreads();
        bhalf8 af[4], bfr[4];
#pragma unroll
        for (int i = 0; i < 4; i++)
            af[i] = *(const bhalf8*)&sA[(wm + i * 16 + lr) * 32 + lk];
#pragma unroll
        for (int i = 0; i < 4; i++)
            bfr[i] = *(const bhalf8*)&sB[(wn + i * 16 + lr) * 32 + lk];
#pragma unroll
        for (int mi = 0; mi < 4; mi++)
#pragma unroll
            for (int ni = 0; ni < 4; ni++)
                acc[mi][ni] = __builtin_amdgcn_mfma_f32_16x16x32_bf16(
                    af[mi], bfr[ni], acc[mi][ni], 0, 0, 0);
    }

    const int sec = bn >> 9;                    // 0=Q 1=K 2=V (uniform per block)
    const float* bp = (sec == 0) ? bq : (sec == 1) ? bk : bv;
    BF* dst = (sec == 0) ? q : (sec == 1) ? kk : vT;
    dst += blockIdx.z * ACTB;
    const int cb = bn & 511;
#pragma unroll
    for (int ni = 0; ni < 4; ni++) {
        const int col = cb + wn + ni * 16 + lr;
        const float bias = bp[col];
#pragma unroll
        for (int mi = 0; mi < 4; mi++) {
            const int row0 = bm + wm + mi * 16 + (lane >> 4) * 4;
#pragma unroll
            for (int r = 0; r < 4; r++) {
                float v = acc[mi][ni][r] + bias;
                if (sec == 2) dst[(long)col * NHW + row0 + r] = __float2bfloat16(v);
                else          dst[(long)(row0 + r) * NC + col] = __float2bfloat16(v);
            }
        }
    }
}

// ---------------------------------------------------------------------------
// Wo GEMM + transpose + residual: out[b][f][i] = sum_c attn[i][c] Wo[f][c] + x.
// ---------------------------------------------------------------------------
__global__ __launch_bounds__(256, 4) void wo_gemm(
    const BF* __restrict__ A, const BF* __restrict__ Bm,
    const float* __restrict__ x, float* __restrict__ out)
{
    const int K = NC;
    __shared__ __align__(16) BF sA[128 * 32];
    __shared__ __align__(16) BF sB[128 * 32];
    const int tid = threadIdx.x;
    const int wave = tid >> 6, lane = tid & 63;
    const int bm = blockIdx.y * 128, bn = blockIdx.x * 128;
    const long ACTB = (long)NHW * NC;
    const BF* Ab = A + blockIdx.z * ACTB + (long)bm * K;
    const BF* Bb = Bm + (long)bn * K;

    const int srow = wave * 32 + (lane >> 2);
    const int sk = (lane & 3) * 8;
    const BF* gA0 = Ab + (long)srow * K + sk;
    const BF* gA1 = gA0 + (long)16 * K;
    const BF* gB0 = Bb + (long)srow * K + sk;
    const BF* gB1 = gB0 + (long)16 * K;
    BF* lA0 = &sA[(wave * 32) * 32];
    BF* lA1 = &sA[(wave * 32 + 16) * 32];
    BF* lB0 = &sB[(wave * 32) * 32];
    BF* lB1 = &sB[(wave * 32 + 16) * 32];

    floatx4 acc[4][4];
#pragma unroll
    for (int i = 0; i < 4; i++)
#pragma unroll
        for (int j = 0; j < 4; j++) acc[i][j] = (floatx4){0.f, 0.f, 0.f, 0.f};

    const int wm = (wave >> 1) * 64, wn = (wave & 1) * 64;
    const int lr = lane & 15, lk = (lane >> 4) * 8;

    for (int k0 = 0; k0 < K; k0 += 32) {
        __syncthreads();
        gload16(gA0 + k0, lA0);
        gload16(gA1 + k0, lA1);
        gload16(gB0 + k0, lB0);
        gload16(gB1 + k0, lB1);
        __syncthreads();
        bhalf8 af[4], bfr[4];
#pragma unroll
        for (int i = 0; i < 4; i++)
            af[i] = *(const bhalf8*)&sA[(wm + i * 16 + lr) * 32 + lk];
#pragma unroll
        for (int i = 0; i < 4; i++)
            bfr[i] = *(const bhalf8*)&sB[(wn + i * 16 + lr) * 32 + lk];
#pragma unroll
        for (int mi = 0; mi < 4; mi++)
#pragma unroll
            for (int ni = 0; ni < 4; ni++)
                acc[mi][ni] = __builtin_amdgcn_mfma_f32_16x16x32_bf16(
                    af[mi], bfr[ni], acc[mi][ni], 0, 0, 0);
    }

    const float* xb = x + blockIdx.z * ACTB;
    float* ob = out + blockIdx.z * ACTB;
#pragma unroll
    for (int ni = 0; ni < 4; ni++) {
        const int col = bn + wn + ni * 16 + lr;      // channel f
#pragma unroll
        for (int mi = 0; mi < 4; mi++) {
            const int row0 = bm + wm + mi * 16 + (lane >> 4) * 4;   // spatial i
            const long a = (long)col * NHW + row0;
            float4 xr = *(const float4*)&xb[a];
            float4 o;
            o.x = acc[mi][ni][0] + xr.x;
            o.y = acc[mi][ni][1] + xr.y;
            o.z = acc[mi][ni][2] + xr.z;
            o.w = acc[mi][ni][3] + xr.w;
            *(float4*)&ob[a] = o;
        }
    }
}

// ---------------------------------------------------------------------------
// PV GEMM, split-K: partial[z][i][c] = sum_{j in segment h} P[i][j] vT[c][j].
// 128x128 tile, m97 staging. Grid (4, 32, chunk*split); z = b*split + h.
// fp32 partial output (combined by pv_combine).
// ---------------------------------------------------------------------------
__global__ __launch_bounds__(256, 3) void pv_gemm(
    const BF* __restrict__ S, const BF* __restrict__ vT,
    float* __restrict__ part, int split)
{
    const long SBl = (long)NHW * NHW, ACTBl = (long)NHW * NC;
    const int Klen = NHW / split;
    const int b = blockIdx.z / split, h = blockIdx.z % split;
    const int bm = blockIdx.y * 128, bn = blockIdx.x * 128;
    const BF* Ab = S + b * SBl + (long)bm * NHW + (long)h * Klen;
    const BF* Bb = vT + b * ACTBl + (long)bn * NHW + (long)h * Klen;

    __shared__ __align__(16) BF sA[128 * 32];
    __shared__ __align__(16) BF sB[128 * 32];
    const int tid = threadIdx.x;
    const int wave = tid >> 6, lane = tid & 63;

    const int srow = wave * 32 + (lane >> 2);
    const int sk = (lane & 3) * 8;
    const BF* gA0 = Ab + (long)srow * NHW + sk;
    const BF* gA1 = gA0 + (long)16 * NHW;
    const BF* gB0 = Bb + (long)srow * NHW + sk;
    const BF* gB1 = gB0 + (long)16 * NHW;
    BF* lA0 = &sA[(wave * 32) * 32];
    BF* lA1 = &sA[(wave * 32 + 16) * 32];
    BF* lB0 = &sB[(wave * 32) * 32];
    BF* lB1 = &sB[(wave * 32 + 16) * 32];

    floatx4 acc[4][4];
#pragma unroll
    for (int i = 0; i < 4; i++)
#pragma unroll
        for (int j = 0; j < 4; j++) acc[i][j] = (floatx4){0.f, 0.f, 0.f, 0.f};

    const int wm = (wave >> 1) * 64, wn = (wave & 1) * 64;
    const int lr = lane & 15, lk = (lane >> 4) * 8;

    for (int k0 = 0; k0 < Klen; k0 += 32) {
        __syncthreads();
        gload16(gA0 + k0, lA0);
        gload16(gA1 + k0, lA1);
        gload16(gB0 + k0, lB0);
        gload16(gB1 + k0, lB1);
        __syncthreads();
        bhalf8 af[4], bfr[4];
#pragma unroll
        for (int i = 0; i < 4; i++)
            af[i] = *(const bhalf8*)&sA[(wm + i * 16 + lr) * 32 + lk];
#pragma unroll
        for (int i = 0; i < 4; i++)
            bfr[i] = *(const bhalf8*)&sB[(wn + i * 16 + lr) * 32 + lk];
#pragma unroll
        for (int mi = 0; mi < 4; mi++)
#pragma unroll
            for (int ni = 0; ni < 4; ni++)
                acc[mi][ni] = __builtin_amdgcn_mfma_f32_16x16x32_bf16(
                    af[mi], bfr[ni], acc[mi][ni], 0, 0, 0);
    }

    float* Pb = part + (long)blockIdx.z * ACTBl;
#pragma unroll
    for (int ni = 0; ni < 4; ni++) {
        const int col = bn + wn + ni * 16 + lr;
#pragma unroll
        for (int mi = 0; mi < 4; mi++) {
            const int row0 = bm + wm + mi * 16 + (lane >> 4) * 4;
#pragma unroll
            for (int r = 0; r < 4; r++)
                Pb[(long)(row0 + r) * NC + col] = acc[mi][ni][r];
        }
    }
}

// ---------------------------------------------------------------------------
// Sum split-K partials -> bf16 attn. total = chunk*ACTB elems.
// ---------------------------------------------------------------------------
__global__ __launch_bounds__(256) void pv_combine(const float* __restrict__ part,
                                                  BF* __restrict__ attn,
                                                  int split, long total) {
    const long ACTB = (long)NHW * NC;          // 2^21
    long idx = ((long)blockIdx.x * 256 + threadIdx.x) * 4;
    if (idx >= total) return;
    long b = idx >> 21;
    long off = idx & (ACTB - 1);
    const float* p = part + (b * split) * ACTB + off;
    float4 a = *(const float4*)p;
    for (int s = 1; s < split; s++) {
        float4 t = *(const float4*)(p + (long)s * ACTB);
        a.x += t.x; a.y += t.y; a.z += t.z; a.w += t.w;
    }
    union { unsigned short u[4]; uint2 v; } o;
    o.u[0] = (unsigned short)f2b(a.x);
    o.u[1] = (unsigned short)f2b(a.y);
    o.u[2] = (unsigned short)f2b(a.z);
    o.u[3] = (unsigned short)f2b(a.w);
    *(uint2*)&attn[idx] = o.v;
}

// ---------------------------------------------------------------------------
__global__ __launch_bounds__(256) void softmax4096(BF* __restrict__ S) {
    const long base = (long)blockIdx.x * 4096 + threadIdx.x * 16;
    const int tid = threadIdx.x, w = tid >> 6;
    bhalf8 u = *(bhalf8*)&S[base];
    bhalf8 u2 = *(bhalf8*)&S[base + 8];
    float v[16];
    float m = -1e30f;
#pragma unroll
    for (int j = 0; j < 8; j++) { v[j] = b2f(u[j]); v[8 + j] = b2f(u2[j]); }
#pragma unroll
    for (int j = 0; j < 16; j++) m = fmaxf(m, v[j]);
#pragma unroll
    for (int o = 32; o; o >>= 1) m = fmaxf(m, __shfl_xor(m, o));
    __shared__ float rm[4], rs[4];
    if ((tid & 63) == 0) rm[w] = m;
    __syncthreads();
    m = fmaxf(fmaxf(rm[0], rm[1]), fmaxf(rm[2], rm[3]));
    float s = 0.f;
#pragma unroll
    for (int j = 0; j < 16; j++) { v[j] = __expf(v[j] - m); s += v[j]; }
#pragma unroll
    for (int o = 32; o; o >>= 1) s += __shfl_xor(s, o);
    if ((tid & 63) == 0) rs[w] = s;
    __syncthreads();
    s = rs[0] + rs[1] + rs[2] + rs[3];
    const float inv = 1.0f / s;
#pragma unroll
    for (int j = 0; j < 8; j++) { u[j] = f2b(v[j] * inv); u2[j] = f2b(v[8 + j] * inv); }
    *(bhalf8*)&S[base] = u;
    *(bhalf8*)&S[base + 8] = u2;
}

// ---------------------------------------------------------------------------
extern "C" void kernel_launch(void* const* d_in, const int* in_sizes, int n_in,
                              void* d_out, int out_size, void* d_ws, size_t ws_size,
                              hipStream_t stream) {
    const float* x     = (const float*)d_in[0];
    const float* gamma = (const float*)d_in[1];
    const float* beta  = (const float*)d_in[2];
    const float* Wq    = (const float*)d_in[3];
    const float* bq    = (const float*)d_in[4];
    const float* Wk    = (const float*)d_in[5];
    const float* bk    = (const float*)d_in[6];
    const float* Wv    = (const float*)d_in[7];
    const float* bv    = (const float*)d_in[8];
    const float* Wo    = (const float*)d_in[9];
    float* out = (float*)d_out;

    const long ACTB = (long)NHW * NC;        // 2M elems / batch
    const long SB   = (long)NHW * NHW;       // 16.7M elems / batch
    const long WSZ  = (long)NC * NC;

    char* ws = (char*)d_ws;
    float* stats = (float*)ws;
    BF* wb = (BF*)(ws + 4096);               // [Wq|Wk|Wv] as [1536,512], then Wo
    BF* q  = wb + 4 * WSZ;
    BF* kk = q + NB * ACTB;
    BF* vT = kk + NB * ACTB;
    BF* R  = vT + NB * ACTB;                 // n, then (S | partials)
    BF* n = R;
    BF* S = R;

    // chunk (batches of S) and split-K factor, from ws room
    const size_t base_need = 4096ull + (size_t)4 * WSZ * 2 + (size_t)3 * NB * ACTB * 2;
    size_t room = (ws_size > base_need) ? ws_size - base_need : 0;
    int chunk = 1, split = 2;
    const int candC[7] = {8, 4, 2, 2, 1, 1, 1};
    const int candS[7] = {2, 2, 4, 2, 8, 4, 2};
    for (int i = 0; i < 7; i++) {
        size_t need = (size_t)candC[i] * SB * 2 +
                      (size_t)candC[i] * candS[i] * ACTB * 4;
        if (room >= need) { chunk = candC[i]; split = candS[i]; break; }
    }
    float* part = (float*)(S + chunk * SB);

    f2b_convert<<<256, 256, 0, stream>>>(Wq, wb + 0 * WSZ, (int)WSZ);
    f2b_convert<<<256, 256, 0, stream>>>(Wk, wb + 1 * WSZ, (int)WSZ);
    f2b_convert<<<256, 256, 0, stream>>>(Wv, wb + 2 * WSZ, (int)WSZ);
    f2b_convert<<<256, 256, 0, stream>>>(Wo, wb + 3 * WSZ, (int)WSZ);

    gn_stats<<<NB * NG, 256, 0, stream>>>(x, stats);
    gn_apply<<<dim3(NHW / 64, NC / 64, NB), 256, 0, stream>>>(x, gamma, beta, stats, n);

    qkv_gemm<<<dim3(12, NHW / 128, NB), 256, 0, stream>>>(
        n, wb, q, kk, vT, bq, bk, bv);

    const float iscl = 0.044194173824159216f;  // 1/sqrt(512)
    for (int b0 = 0; b0 < NB; b0 += chunk) {
        sgemm<<<dim3(NHW / 128, NHW / 128, chunk), 256, 0, stream>>>(
            q + b0 * ACTB, ACTB, kk + b0 * ACTB, ACTB, S, SB,
            NHW, NHW, NC, iscl);
        softmax4096<<<NHW * chunk, 256, 0, stream>>>(S);
        pv_gemm<<<dim3(NC / 128, NHW / 128, chunk * split), 256, 0, stream>>>(
            S, vT + b0 * ACTB, part, split);
        pv_combine<<<(unsigned)(chunk * ACTB / 1024), 256, 0, stream>>>(
            part, q + b0 * ACTB, split, chunk * ACTB);   // attn overwrites Q
    }

    wo_gemm<<<dim3(NC / 128, NHW / 128, NB), 256, 0, stream>>>(
        q, wb + 3 * WSZ, x, out);
}